// Round 1
// baseline (327.330 us; speedup 1.0000x reference)
//
#include <hip/hip_runtime.h>

#define H 512
#define W 512
#define NPIX (H * W)
#define BIG_I 1073741824   // 2^30
#define BIG_F 1.0e6f

// ---- workspace layout ----
// [0, NPIX) int32            : labels (parent pointers, then roots)
// [NPIX, 2*NPIX) float       : distance transform buffer
// byte offset 2*NPIX*4       : Scal block
struct Scal {
  float soa;             // sum(1 - img), atomicAdd target (pre-zeroed)
  unsigned int min_bits; // float-as-uint atomicMin target for masked dist min
  float cluster;         // sum of img over start_mask, atomicAdd target
  int sl, el, both;      // start/end labels (-1 if unused), both flag
  float r0, r1;          // img at the two points
  int p0idx;             // linear index of point 0
};

// ---- union-find (ECL-CC style): root of a tree is the MIN index ----
__device__ __forceinline__ int rep(int* lab, int v) {
  int cur = lab[v];
  if (cur == v) return v;
  int prev = v, next;
  while (cur > (next = lab[cur])) {  // path-compress while walking up
    lab[prev] = next;
    prev = cur;
    cur = next;
  }
  return cur;
}

__device__ __forceinline__ void unite(int* lab, int a, int b) {
  int ra = rep(lab, a);
  int rb = rep(lab, b);
  while (ra != rb) {
    if (ra < rb) { int t = ra; ra = rb; rb = t; }   // hook larger root under smaller
    int old = atomicCAS(&lab[ra], ra, rb);
    if (old == ra) break;       // successfully linked
    ra = rep(lab, old);         // ra was hooked elsewhere meanwhile; retry
    rb = rep(lab, rb);
  }
}

// ---- 1: init labels + soa reduction ----
__global__ void k_init(const float* __restrict__ img, int* __restrict__ lab,
                       Scal* __restrict__ s) {
  int p = blockIdx.x * blockDim.x + threadIdx.x;
  float x = img[p];
  bool fg = rintf(x) > 0.5f;             // jnp.round = round-half-even = rintf
  lab[p] = fg ? p : BIG_I;
  float v = 1.0f - x;
  for (int o = 32; o; o >>= 1) v += __shfl_down(v, o, 64);
  __shared__ float ls[4];
  int lane = threadIdx.x & 63, wv = threadIdx.x >> 6;
  if (lane == 0) ls[wv] = v;
  __syncthreads();
  if (threadIdx.x == 0) atomicAdd(&s->soa, ls[0] + ls[1] + ls[2] + ls[3]);
}

// ---- 2: merge 8-connected foreground neighbors (each undirected edge once) ----
__global__ void k_merge(int* __restrict__ lab) {
  int p = blockIdx.x * blockDim.x + threadIdx.x;
  if (lab[p] == BIG_I) return;
  int i = p >> 9, j = p & (W - 1);
  // neighbors above (3) + left (1)
  if (i > 0) {
    int q = p - W;
    if (j > 0     && lab[q - 1] != BIG_I) unite(lab, p, q - 1);
    if (             lab[q]     != BIG_I) unite(lab, p, q);
    if (j < W - 1 && lab[q + 1] != BIG_I) unite(lab, p, q + 1);
  }
  if (j > 0 && lab[p - 1] != BIG_I) unite(lab, p, p - 1);
}

// ---- 3: flatten to final labels ----
__global__ void k_flatten(int* __restrict__ lab) {
  int p = blockIdx.x * blockDim.x + threadIdx.x;
  if (lab[p] != BIG_I) lab[p] = rep(lab, p);
}

// ---- 4: scalars at the two points ----
__global__ void k_scalars(const float* __restrict__ img, const int* __restrict__ pts,
                          const int* __restrict__ lab, Scal* __restrict__ s) {
  int p0 = pts[0] * W + pts[1];
  int p1 = pts[2] * W + pts[3];
  int sl = lab[p0], el = lab[p1];
  int both = (sl != BIG_I) && (el != BIG_I);
  s->both = both;
  s->sl = both ? sl : -1;   // -1 matches no pixel -> empty masks when !both
  s->el = both ? el : -1;
  s->r0 = img[p0];
  s->r1 = img[p1];
  s->p0idx = p0;
  s->min_bits = __float_as_uint(BIG_F);
  s->cluster = 0.0f;
}

// ---- 5: L1 DT pass along axis 0 (one thread per column) ----
__global__ void k_dt_col(const int* __restrict__ lab, const Scal* __restrict__ s,
                         float* __restrict__ dist) {
  int j = blockIdx.x * blockDim.x + threadIdx.x;
  if (j >= W) return;
  int el = s->el;
  float c = BIG_F;
  for (int i = 0; i < H; ++i) {
    float d = (lab[i * W + j] == el) ? 0.0f : BIG_F;
    c = fminf(d, c + 1.0f);
    dist[i * W + j] = c;
  }
  c = BIG_F;
  for (int i = H - 1; i >= 0; --i) {
    float d = (lab[i * W + j] == el) ? 0.0f : BIG_F;
    c = fminf(d, c + 1.0f);
    dist[i * W + j] = fminf(dist[i * W + j], c);
  }
}

// ---- 6: L1 DT pass along axis 1 (one thread per row, in place) ----
__global__ void k_dt_row(float* __restrict__ dist) {
  int i = blockIdx.x * blockDim.x + threadIdx.x;
  if (i >= H) return;
  float* row = dist + i * W;
  float c = BIG_F;
  for (int j = 0; j < W; ++j) { c = fminf(row[j], c + 1.0f); row[j] = c; }
  c = BIG_F;
  for (int j = W - 1; j >= 0; --j) { c = fminf(row[j], c + 1.0f); row[j] = c; }
}

// ---- 7: masked reductions over the start component ----
__global__ void k_reduce(const float* __restrict__ img, const int* __restrict__ lab,
                         const float* __restrict__ dist, Scal* __restrict__ s) {
  int p = blockIdx.x * blockDim.x + threadIdx.x;
  int sl = s->sl;
  bool in = (lab[p] == sl);             // sl==-1 -> empty mask
  float dv = in ? dist[p] : BIG_F;
  float cv = in ? img[p] : 0.0f;
  for (int o = 32; o; o >>= 1) {
    dv = fminf(dv, __shfl_down(dv, o, 64));
    cv += __shfl_down(cv, o, 64);
  }
  __shared__ float smin[4], ssum[4];
  int lane = threadIdx.x & 63, wv = threadIdx.x >> 6;
  if (lane == 0) { smin[wv] = dv; ssum[wv] = cv; }
  __syncthreads();
  if (threadIdx.x == 0) {
    float m = fminf(fminf(smin[0], smin[1]), fminf(smin[2], smin[3]));
    float su = ssum[0] + ssum[1] + ssum[2] + ssum[3];
    atomicMin(&s->min_bits, __float_as_uint(m));   // all values >= 0: uint order == float order
    atomicAdd(&s->cluster, su);
  }
}

// ---- 8: finalize ----
__global__ void k_final(const float* __restrict__ dist, const Scal* __restrict__ s,
                        float* __restrict__ out) {
  float fallback = (2.0f - (s->r0 + s->r1)) * 100.0f;
  out[0] = fallback;
  float min_d = fminf(dist[s->p0idx], __uint_as_float(s->min_bits));
  float soa = s->soa;
  out[1] = s->both ? (min_d * soa * 10.0f * soa) : fallback;
  out[2] = s->both ? (s->cluster * 90.0f) : fallback;
}

extern "C" void kernel_launch(void* const* d_in, const int* in_sizes, int n_in,
                              void* d_out, int out_size, void* d_ws, size_t ws_size,
                              hipStream_t stream) {
  // reference returns only batch element 3 of (ls, gl, cp)
  const float* img = (const float*)d_in[0] + 3 * NPIX;   // result_given[3,0]
  const int* pts = (const int*)d_in[1] + 3 * 4;          // points_given[3]
  float* out = (float*)d_out;

  int* lab = (int*)d_ws;
  float* dist = (float*)d_ws + NPIX;
  Scal* s = (Scal*)((char*)d_ws + (size_t)2 * NPIX * 4);

  hipMemsetAsync(s, 0, sizeof(Scal), stream);  // only ->soa must be 0 pre-init

  const int B = 256, G = NPIX / B;
  k_init<<<G, B, 0, stream>>>(img, lab, s);
  k_merge<<<G, B, 0, stream>>>(lab);
  k_flatten<<<G, B, 0, stream>>>(lab);
  k_scalars<<<1, 1, 0, stream>>>(img, pts, lab, s);
  k_dt_col<<<2, 256, 0, stream>>>(lab, s, dist);
  k_dt_row<<<2, 256, 0, stream>>>(dist);
  k_reduce<<<G, B, 0, stream>>>(img, lab, dist, s);
  k_final<<<1, 1, 0, stream>>>(dist, s, out);
}

// Round 2
// 298.923 us; speedup vs baseline: 1.0950x; 1.0950x over previous
//
#include <hip/hip_runtime.h>

#define H 512
#define W 512
#define NPIX (H * W)
#define BIG_I 1073741824   // 2^30
#define BIG_F 1.0e6f
#define TS 64              // CCL tile side
#define TPIX (TS * TS)     // 4096 px/tile

// ---- workspace layout ----
// [0, NPIX) int32            : labels
// [NPIX, 2*NPIX) float       : distance transform buffer
// byte offset 2*NPIX*4       : Scal block
struct Scal {
  float soa;             // sum(1 - img), atomicAdd (memset 0)
  unsigned int min_bits; // float-bits atomicMin target (set in k_scalars)
  float cluster;         // sum img over start_mask (set in k_scalars)
  unsigned int done;     // reduce-block completion counter (memset 0)
  int sl, el, both;
  float r0, r1;
  int p0idx;
};

// ================= union-find, global (min-index roots) =================
__device__ __forceinline__ int rep(int* lab, int v) {
  int cur = lab[v];
  if (cur == v) return v;
  int prev = v, next;
  while (cur > (next = lab[cur])) { lab[prev] = next; prev = cur; cur = next; }
  return cur;
}
__device__ __forceinline__ void unite(int* lab, int a, int b) {
  int ra = rep(lab, a), rb = rep(lab, b);
  while (ra != rb) {
    if (ra < rb) { int t = ra; ra = rb; rb = t; }
    int old = atomicCAS(&lab[ra], ra, rb);
    if (old == ra) break;
    ra = rep(lab, old);
    rb = rep(lab, rb);
  }
}
// ================= union-find, LDS-local =================
__device__ __forceinline__ int repL(int* lab, int v) {
  int cur = lab[v];
  if (cur == v) return v;
  int prev = v, next;
  while (cur > (next = lab[cur])) { lab[prev] = next; prev = cur; cur = next; }
  return cur;
}
__device__ __forceinline__ void uniteL(int* lab, int a, int b) {
  int ra = repL(lab, a), rb = repL(lab, b);
  while (ra != rb) {
    if (ra < rb) { int t = ra; ra = rb; rb = t; }
    int old = atomicCAS(&lab[ra], ra, rb);
    if (old == ra) break;
    ra = repL(lab, old);
    rb = repL(lab, rb);
  }
}

// ---- 1: per-tile LDS CCL + soa reduction (fuses old init+merge-local) ----
__global__ __launch_bounds__(256) void k_local(const float* __restrict__ img,
                                               int* __restrict__ lab,
                                               Scal* __restrict__ s) {
  __shared__ int sl[TPIX];          // 16 KB; -1 = background
  __shared__ float red[4];
  int t = threadIdx.x;
  int tileX = (blockIdx.x & 7) * TS;
  int tileY = (blockIdx.x >> 3) * TS;
  float acc = 0.0f;
  #pragma unroll
  for (int k = 0; k < 16; ++k) {
    int li = k * 256 + t;
    int gp = (tileY + (li >> 6)) * W + tileX + (li & 63);
    float x = img[gp];
    acc += 1.0f - x;
    sl[li] = (rintf(x) > 0.5f) ? li : -1;
  }
  __syncthreads();
  // union in-tile 8-neighbor edges (up-left, up, up-right, left)
  for (int k = 0; k < 16; ++k) {
    int li = k * 256 + t;
    if (sl[li] < 0) continue;
    int ly = li >> 6, lx = li & 63;
    if (ly > 0) {
      int q = li - TS;
      if (lx > 0      && sl[q - 1] >= 0) uniteL(sl, li, q - 1);
      if (               sl[q]     >= 0) uniteL(sl, li, q);
      if (lx < TS - 1 && sl[q + 1] >= 0) uniteL(sl, li, q + 1);
    }
    if (lx > 0 && sl[li - 1] >= 0) uniteL(sl, li, li - 1);
  }
  __syncthreads();
  // flatten locally, emit global parent = global index of local root
  for (int k = 0; k < 16; ++k) {
    int li = k * 256 + t;
    int gp = (tileY + (li >> 6)) * W + tileX + (li & 63);
    if (sl[li] < 0) lab[gp] = BIG_I;
    else {
      int r = repL(sl, li);
      lab[gp] = (tileY + (r >> 6)) * W + tileX + (r & 63);
    }
  }
  // soa partial
  for (int o = 32; o; o >>= 1) acc += __shfl_down(acc, o, 64);
  int lane = t & 63, wv = t >> 6;
  if (lane == 0) red[wv] = acc;
  __syncthreads();
  if (t == 0) atomicAdd(&s->soa, red[0] + red[1] + red[2] + red[3]);
}

// ---- 2: merge only edges crossing tile boundaries ----
__global__ void k_border(int* __restrict__ lab) {
  int p = blockIdx.x * blockDim.x + threadIdx.x;
  if (lab[p] == BIG_I) return;
  int i = p >> 9, j = p & (W - 1);
  int ly = i & (TS - 1), lx = j & (TS - 1);
  bool top = (ly == 0) && (i > 0);
  if (top) {
    int q = p - W;
    if (j > 0     && lab[q - 1] != BIG_I) unite(lab, p, q - 1);
    if (             lab[q]     != BIG_I) unite(lab, p, q);
    if (j < W - 1 && lab[q + 1] != BIG_I) unite(lab, p, q + 1);
  }
  if (lx == 0 && j > 0) {
    if (lab[p - 1] != BIG_I) unite(lab, p, p - 1);
    if (!top && i > 0 && lab[p - W - 1] != BIG_I) unite(lab, p, p - W - 1);
  }
  if (lx == TS - 1 && j < W - 1 && !top && i > 0) {
    if (lab[p - W + 1] != BIG_I) unite(lab, p, p - W + 1);
  }
}

// ---- 3: flatten to final labels ----
__global__ void k_flatten(int* __restrict__ lab) {
  int p = blockIdx.x * blockDim.x + threadIdx.x;
  if (lab[p] != BIG_I) lab[p] = rep(lab, p);
}

// ---- 4: scalars at the two points ----
__global__ void k_scalars(const float* __restrict__ img, const int* __restrict__ pts,
                          const int* __restrict__ lab, Scal* __restrict__ s) {
  int p0 = pts[0] * W + pts[1];
  int p1 = pts[2] * W + pts[3];
  int sl = lab[p0], el = lab[p1];
  int both = (sl != BIG_I) && (el != BIG_I);
  s->both = both;
  s->sl = both ? sl : -1;
  s->el = both ? el : -1;
  s->r0 = img[p0];
  s->r1 = img[p1];
  s->p0idx = p0;
  s->min_bits = __float_as_uint(BIG_F);
  s->cluster = 0.0f;
}

// ---- 5: L1 DT along axis 0 (one thread per column) ----
__global__ void k_dt_col(const int* __restrict__ lab, const Scal* __restrict__ s,
                         float* __restrict__ dist) {
  int j = blockIdx.x * blockDim.x + threadIdx.x;
  if (j >= W) return;
  int el = s->el;
  float c = BIG_F;
  for (int i = 0; i < H; ++i) {
    float d = (lab[i * W + j] == el) ? 0.0f : BIG_F;
    c = fminf(d, c + 1.0f);
    dist[i * W + j] = c;
  }
  c = BIG_F;
  for (int i = H - 1; i >= 0; --i) {
    float d = (lab[i * W + j] == el) ? 0.0f : BIG_F;
    c = fminf(d, c + 1.0f);
    dist[i * W + j] = fminf(dist[i * W + j], c);
  }
}

// ---- 6: L1 DT along axis 1 (one thread per row, in place) ----
__global__ void k_dt_row(float* __restrict__ dist) {
  int i = blockIdx.x * blockDim.x + threadIdx.x;
  if (i >= H) return;
  float* row = dist + i * W;
  float c = BIG_F;
  for (int j = 0; j < W; ++j) { c = fminf(row[j], c + 1.0f); row[j] = c; }
  c = BIG_F;
  for (int j = W - 1; j >= 0; --j) { c = fminf(row[j], c + 1.0f); row[j] = c; }
}

// ---- 7: masked reductions + fused finalize (last block) ----
__global__ void k_reduce(const float* __restrict__ img, const int* __restrict__ lab,
                         const float* __restrict__ dist, Scal* __restrict__ s,
                         float* __restrict__ out) {
  int p = blockIdx.x * blockDim.x + threadIdx.x;
  int sl = s->sl;
  bool in = (lab[p] == sl);
  float dv = in ? dist[p] : BIG_F;
  float cv = in ? img[p] : 0.0f;
  for (int o = 32; o; o >>= 1) {
    dv = fminf(dv, __shfl_down(dv, o, 64));
    cv += __shfl_down(cv, o, 64);
  }
  __shared__ float smin[4], ssum[4];
  int lane = threadIdx.x & 63, wv = threadIdx.x >> 6;
  if (lane == 0) { smin[wv] = dv; ssum[wv] = cv; }
  __syncthreads();
  if (threadIdx.x == 0) {
    float m = fminf(fminf(smin[0], smin[1]), fminf(smin[2], smin[3]));
    float su = ssum[0] + ssum[1] + ssum[2] + ssum[3];
    atomicMin(&s->min_bits, __float_as_uint(m));
    atomicAdd(&s->cluster, su);
    __threadfence();
    unsigned old = atomicAdd(&s->done, 1u);
    if (old == gridDim.x - 1) {          // last block finalizes
      float fallback = (2.0f - (s->r0 + s->r1)) * 100.0f;
      out[0] = fallback;
      unsigned mb = atomicOr(&s->min_bits, 0u);      // coherent read
      float cl = atomicAdd(&s->cluster, 0.0f);       // coherent read
      float min_d = fminf(dist[s->p0idx], __uint_as_float(mb));
      float soa = s->soa;
      out[1] = s->both ? (min_d * soa * 10.0f * soa) : fallback;
      out[2] = s->both ? (cl * 90.0f) : fallback;
    }
  }
}

extern "C" void kernel_launch(void* const* d_in, const int* in_sizes, int n_in,
                              void* d_out, int out_size, void* d_ws, size_t ws_size,
                              hipStream_t stream) {
  // reference returns only batch element 3 of (ls, gl, cp)
  const float* img = (const float*)d_in[0] + 3 * NPIX;   // result_given[3,0]
  const int* pts = (const int*)d_in[1] + 3 * 4;          // points_given[3]
  float* out = (float*)d_out;

  int* lab = (int*)d_ws;
  float* dist = (float*)d_ws + NPIX;
  Scal* s = (Scal*)((char*)d_ws + (size_t)2 * NPIX * 4);

  hipMemsetAsync(s, 0, sizeof(Scal), stream);  // soa=0, done=0

  const int B = 256, G = NPIX / B;
  k_local<<<64, 256, 0, stream>>>(img, lab, s);
  k_border<<<G, B, 0, stream>>>(lab);
  k_flatten<<<G, B, 0, stream>>>(lab);
  k_scalars<<<1, 1, 0, stream>>>(img, pts, lab, s);
  k_dt_col<<<2, 256, 0, stream>>>(lab, s, dist);
  k_dt_row<<<2, 256, 0, stream>>>(dist);
  k_reduce<<<G, B, 0, stream>>>(img, lab, dist, s, out);
}

// Round 3
// 176.639 us; speedup vs baseline: 1.8531x; 1.6923x over previous
//
#include <hip/hip_runtime.h>

#define H 512
#define W 512
#define NPIX (H * W)
#define BIG_I 1073741824   // 2^30
#define BIG_F 1.0e6f
#define INF30 1.0e30f
#define TS 64              // CCL tile side
#define TPIX (TS * TS)

// ---- workspace layout ----
// [0, NPIX) int32       : labels
// [NPIX, 2*NPIX) float  : distance transform buffer
// then Scal (64B-aligned), then Af[8*512], Ab[8*512] floats
struct Scal {
  float soa;
  unsigned int min_bits;
  float cluster;
  unsigned int done;
  int sl, el, both;
  float r0, r1;
  int p0idx;
};

// ================= union-find (min-index roots) =================
__device__ __forceinline__ int rep(int* lab, int v) {
  int cur = lab[v];
  if (cur == v) return v;
  int prev = v, next;
  while (cur > (next = lab[cur])) { lab[prev] = next; prev = cur; cur = next; }
  return cur;
}
__device__ __forceinline__ void unite(int* lab, int a, int b) {
  int ra = rep(lab, a), rb = rep(lab, b);
  while (ra != rb) {
    if (ra < rb) { int t = ra; ra = rb; rb = t; }
    int old = atomicCAS(&lab[ra], ra, rb);
    if (old == ra) break;
    ra = rep(lab, old);
    rb = rep(lab, rb);
  }
}

// ---- 1: per-tile LDS CCL + soa reduction ----
__global__ __launch_bounds__(256) void k_local(const float* __restrict__ img,
                                               int* __restrict__ lab,
                                               Scal* __restrict__ s) {
  __shared__ int sl[TPIX];
  __shared__ float red[4];
  int t = threadIdx.x;
  int tileX = (blockIdx.x & 7) * TS;
  int tileY = (blockIdx.x >> 3) * TS;
  float acc = 0.0f;
  #pragma unroll
  for (int k = 0; k < 16; ++k) {
    int li = k * 256 + t;
    int gp = (tileY + (li >> 6)) * W + tileX + (li & 63);
    float x = img[gp];
    acc += 1.0f - x;
    sl[li] = (rintf(x) > 0.5f) ? li : -1;
  }
  __syncthreads();
  for (int k = 0; k < 16; ++k) {
    int li = k * 256 + t;
    if (sl[li] < 0) continue;
    int ly = li >> 6, lx = li & 63;
    if (ly > 0) {
      int q = li - TS;
      if (lx > 0      && sl[q - 1] >= 0) unite(sl, li, q - 1);
      if (               sl[q]     >= 0) unite(sl, li, q);
      if (lx < TS - 1 && sl[q + 1] >= 0) unite(sl, li, q + 1);
    }
    if (lx > 0 && sl[li - 1] >= 0) unite(sl, li, li - 1);
  }
  __syncthreads();
  for (int k = 0; k < 16; ++k) {
    int li = k * 256 + t;
    int gp = (tileY + (li >> 6)) * W + tileX + (li & 63);
    if (sl[li] < 0) lab[gp] = BIG_I;
    else {
      int r = rep(sl, li);
      lab[gp] = (tileY + (r >> 6)) * W + tileX + (r & 63);
    }
  }
  for (int o = 32; o; o >>= 1) acc += __shfl_down(acc, o, 64);
  int lane = t & 63, wv = t >> 6;
  if (lane == 0) red[wv] = acc;
  __syncthreads();
  if (t == 0) atomicAdd(&s->soa, red[0] + red[1] + red[2] + red[3]);
}

// ---- 2: merge edges crossing tile boundaries ----
__global__ void k_border(int* __restrict__ lab) {
  int p = blockIdx.x * blockDim.x + threadIdx.x;
  if (lab[p] == BIG_I) return;
  int i = p >> 9, j = p & (W - 1);
  int ly = i & (TS - 1), lx = j & (TS - 1);
  bool top = (ly == 0) && (i > 0);
  if (top) {
    int q = p - W;
    if (j > 0     && lab[q - 1] != BIG_I) unite(lab, p, q - 1);
    if (             lab[q]     != BIG_I) unite(lab, p, q);
    if (j < W - 1 && lab[q + 1] != BIG_I) unite(lab, p, q + 1);
  }
  if (lx == 0 && j > 0) {
    if (lab[p - 1] != BIG_I) unite(lab, p, p - 1);
    if (!top && i > 0 && lab[p - W - 1] != BIG_I) unite(lab, p, p - W - 1);
  }
  if (lx == TS - 1 && j < W - 1 && !top && i > 0) {
    if (lab[p - W + 1] != BIG_I) unite(lab, p, p - W + 1);
  }
}

// ---- 3: flatten ----
__global__ void k_flatten(int* __restrict__ lab) {
  int p = blockIdx.x * blockDim.x + threadIdx.x;
  if (lab[p] != BIG_I) lab[p] = rep(lab, p);
}

// ---- 4: scalars at the two points ----
__global__ void k_scalars(const float* __restrict__ img, const int* __restrict__ pts,
                          const int* __restrict__ lab, Scal* __restrict__ s) {
  int p0 = pts[0] * W + pts[1];
  int p1 = pts[2] * W + pts[3];
  int sl = lab[p0], el = lab[p1];
  int both = (sl != BIG_I) && (el != BIG_I);
  s->both = both;
  s->sl = both ? sl : -1;
  s->el = both ? el : -1;
  s->r0 = img[p0];
  s->r1 = img[p1];
  s->p0idx = p0;
  s->min_bits = __float_as_uint(BIG_F);
  s->cluster = 0.0f;
}

// ---- 5: L1 DT along axis 1 (rows) — wave-per-row prefix/suffix-min scan ----
// fwd[j] = j + min_{k<=j}(d[k]-k); bwd[j] = -j + min_{k>=j}(d[k]+k); out = min.
__global__ __launch_bounds__(256) void k_dt_rows(const int* __restrict__ lab,
                                                 const Scal* __restrict__ s,
                                                 float* __restrict__ dist) {
  int lane = threadIdx.x & 63;
  int row = blockIdx.x * 4 + (threadIdx.x >> 6);
  int el = s->el;
  const int4* lp = (const int4*)(lab + row * W) + lane * 2;
  int4 a = lp[0], b = lp[1];
  float d[8];
  d[0] = (a.x == el) ? 0.f : BIG_F; d[1] = (a.y == el) ? 0.f : BIG_F;
  d[2] = (a.z == el) ? 0.f : BIG_F; d[3] = (a.w == el) ? 0.f : BIG_F;
  d[4] = (b.x == el) ? 0.f : BIG_F; d[5] = (b.y == el) ? 0.f : BIG_F;
  d[6] = (b.z == el) ? 0.f : BIG_F; d[7] = (b.w == el) ? 0.f : BIG_F;
  int j0 = lane * 8;
  float pf[8], sb[8];
  float m = INF30;
  #pragma unroll
  for (int r = 0; r < 8; ++r) { m = fminf(m, d[r] - (float)(j0 + r)); pf[r] = m; }
  float tf = m;
  m = INF30;
  #pragma unroll
  for (int r = 7; r >= 0; --r) { m = fminf(m, d[r] + (float)(j0 + r)); sb[r] = m; }
  float tb = m;
  // wave-level inclusive scans, then shift for exclusive carries
  float v = tf;
  #pragma unroll
  for (int off = 1; off < 64; off <<= 1) {
    float u = __shfl_up(v, off, 64);
    if (lane >= off) v = fminf(v, u);
  }
  float ef = __shfl_up(v, 1, 64); if (lane == 0) ef = INF30;
  v = tb;
  #pragma unroll
  for (int off = 1; off < 64; off <<= 1) {
    float u = __shfl_down(v, off, 64);
    if (lane < 64 - off) v = fminf(v, u);
  }
  float eb = __shfl_down(v, 1, 64); if (lane == 63) eb = INF30;
  float o[8];
  #pragma unroll
  for (int r = 0; r < 8; ++r) {
    float j = (float)(j0 + r);
    o[r] = fminf(j + fminf(ef, pf[r]), -j + fminf(eb, sb[r]));
  }
  float4* dp = (float4*)(dist + row * W) + lane * 2;
  dp[0] = make_float4(o[0], o[1], o[2], o[3]);
  dp[1] = make_float4(o[4], o[5], o[6], o[7]);
}

// ---- 6a: column pass level 1 — per (64-row block, column) aggregates ----
__global__ void k_dt_colA(const float* __restrict__ dist,
                          float* __restrict__ Af, float* __restrict__ Ab) {
  int t = blockIdx.x * blockDim.x + threadIdx.x;   // 0..4095
  int b = t >> 9, j = t & (W - 1);
  int i0 = b * 64;
  float fa = INF30, fb = INF30;
  #pragma unroll 8
  for (int il = 0; il < 64; ++il) {
    float v = dist[(i0 + il) * W + j];
    float fi = (float)(i0 + il);
    fa = fminf(fa, v - fi);
    fb = fminf(fb, v + fi);
  }
  Af[t] = fa;
  Ab[t] = fb;
}

// ---- 6b: column pass level 2 — apply with inline carry scan ----
__global__ __launch_bounds__(256) void k_dt_colB(float* __restrict__ dist,
                                                 const float* __restrict__ Af,
                                                 const float* __restrict__ Ab) {
  int t = blockIdx.x * blockDim.x + threadIdx.x;
  int b = t >> 9, j = t & (W - 1);
  float cf = INF30, cb = INF30;
  #pragma unroll
  for (int bb = 0; bb < 8; ++bb) {
    float af = Af[bb * W + j];
    float ab = Ab[bb * W + j];
    if (bb < b) cf = fminf(cf, af);
    if (bb > b) cb = fminf(cb, ab);
  }
  int i0 = b * 64;
  float r[64], f[64];
  float m = cf;
  #pragma unroll
  for (int il = 0; il < 64; ++il) {
    r[il] = dist[(i0 + il) * W + j];
    float fi = (float)(i0 + il);
    m = fminf(m, r[il] - fi);
    f[il] = fi + m;
  }
  m = cb;
  #pragma unroll
  for (int il = 63; il >= 0; --il) {
    float fi = (float)(i0 + il);
    m = fminf(m, r[il] + fi);
    dist[(i0 + il) * W + j] = fminf(f[il], m - fi);
  }
}

// ---- 7: masked reductions + fused finalize ----
__global__ void k_reduce(const float* __restrict__ img, const int* __restrict__ lab,
                         const float* __restrict__ dist, Scal* __restrict__ s,
                         float* __restrict__ out) {
  int p = blockIdx.x * blockDim.x + threadIdx.x;
  int sl = s->sl;
  bool in = (lab[p] == sl);
  float dv = in ? dist[p] : BIG_F;
  float cv = in ? img[p] : 0.0f;
  for (int o = 32; o; o >>= 1) {
    dv = fminf(dv, __shfl_down(dv, o, 64));
    cv += __shfl_down(cv, o, 64);
  }
  __shared__ float smin[4], ssum[4];
  int lane = threadIdx.x & 63, wv = threadIdx.x >> 6;
  if (lane == 0) { smin[wv] = dv; ssum[wv] = cv; }
  __syncthreads();
  if (threadIdx.x == 0) {
    float mm = fminf(fminf(smin[0], smin[1]), fminf(smin[2], smin[3]));
    float su = ssum[0] + ssum[1] + ssum[2] + ssum[3];
    atomicMin(&s->min_bits, __float_as_uint(mm));
    atomicAdd(&s->cluster, su);
    __threadfence();
    unsigned old = atomicAdd(&s->done, 1u);
    if (old == gridDim.x - 1) {
      float fallback = (2.0f - (s->r0 + s->r1)) * 100.0f;
      out[0] = fallback;
      unsigned mb = atomicOr(&s->min_bits, 0u);
      float cl = atomicAdd(&s->cluster, 0.0f);
      float min_d = fminf(dist[s->p0idx], __uint_as_float(mb));
      float soa = s->soa;
      out[1] = s->both ? (min_d * soa * 10.0f * soa) : fallback;
      out[2] = s->both ? (cl * 90.0f) : fallback;
    }
  }
}

extern "C" void kernel_launch(void* const* d_in, const int* in_sizes, int n_in,
                              void* d_out, int out_size, void* d_ws, size_t ws_size,
                              hipStream_t stream) {
  const float* img = (const float*)d_in[0] + 3 * NPIX;   // result_given[3,0]
  const int* pts = (const int*)d_in[1] + 3 * 4;          // points_given[3]
  float* out = (float*)d_out;

  int* lab = (int*)d_ws;
  float* dist = (float*)d_ws + NPIX;
  char* base = (char*)d_ws + (size_t)2 * NPIX * 4;
  Scal* s = (Scal*)base;
  float* Af = (float*)(base + 64);
  float* Ab = Af + 8 * W;

  hipMemsetAsync(s, 0, sizeof(Scal), stream);  // soa=0, done=0

  const int B = 256, G = NPIX / B;
  k_local<<<64, 256, 0, stream>>>(img, lab, s);
  k_border<<<G, B, 0, stream>>>(lab);
  k_flatten<<<G, B, 0, stream>>>(lab);
  k_scalars<<<1, 1, 0, stream>>>(img, pts, lab, s);
  k_dt_rows<<<H / 4, 256, 0, stream>>>(lab, s, dist);
  k_dt_colA<<<16, 256, 0, stream>>>(dist, Af, Ab);
  k_dt_colB<<<16, 256, 0, stream>>>(dist, Af, Ab);
  k_reduce<<<G, B, 0, stream>>>(img, lab, dist, s, out);
}

// Round 4
// 119.450 us; speedup vs baseline: 2.7403x; 1.4788x over previous
//
#include <hip/hip_runtime.h>

#define H 512
#define W 512
#define NPIX (H * W)
#define BIG_I 1073741824   // 2^30
#define BIG_F 1.0e6f
#define INF30 1.0e30f
#define TS 32              // CCL tile side (32x32 -> 256 blocks, 1/CU)

// ---- workspace layout ----
// [0, NPIX) int32       : labels
// [NPIX, 2*NPIX) float  : distance transform buffer
// then Scal (64B), then Af[16*512], Ab[16*512] floats
struct Scal {
  float soa;             // memset 0, atomicAdd
  unsigned int min_bits; // set by dt_rows, atomicMin by reduce
  float cluster;         // memset 0, atomicAdd
  unsigned int done;     // memset 0
  int both;
  float r0, r1;
};

// ================= union-find (min-index roots) =================
__device__ __forceinline__ int rep(int* lab, int v) {
  int cur = lab[v];
  if (cur == v) return v;
  int prev = v, next;
  while (cur > (next = lab[cur])) { lab[prev] = next; prev = cur; cur = next; }
  return cur;
}
__device__ __forceinline__ void unite(int* lab, int a, int b) {
  int ra = rep(lab, a), rb = rep(lab, b);
  while (ra != rb) {
    if (ra < rb) { int t = ra; ra = rb; rb = t; }
    int old = atomicCAS(&lab[ra], ra, rb);
    if (old == ra) break;
    ra = rep(lab, old);
    rb = rep(lab, rb);
  }
}
__device__ __forceinline__ int root_ro(const int* __restrict__ lab, int v) {
  int n;
  while ((n = lab[v]) != v) v = n;   // parents strictly decrease; terminates at root
  return v;
}

// ---- 1: per-tile LDS CCL (row-run init + vertical unions) + soa ----
__global__ __launch_bounds__(256) void k_local(const float* __restrict__ img,
                                               int* __restrict__ lab,
                                               Scal* __restrict__ s) {
  __shared__ int sl[TS * TS];
  __shared__ unsigned rm[TS];
  __shared__ float red[4];
  int t = threadIdx.x;
  int tileX = (blockIdx.x & 15) * TS;
  int tileY = (blockIdx.x >> 4) * TS;
  if (t < TS) rm[t] = 0u;
  __syncthreads();
  int r = t >> 3, c0 = (t & 7) * 4;   // thread owns 4 consecutive px of row r
  const float4 x4 = *(const float4*)(img + (tileY + r) * W + tileX + c0);
  float acc = 4.0f - (x4.x + x4.y + x4.z + x4.w);
  unsigned nib = (rintf(x4.x) > 0.5f ? 1u : 0u) | (rintf(x4.y) > 0.5f ? 2u : 0u)
               | (rintf(x4.z) > 0.5f ? 4u : 0u) | (rintf(x4.w) > 0.5f ? 8u : 0u);
  atomicOr(&rm[r], nib << c0);
  __syncthreads();
  unsigned m = rm[r];
  #pragma unroll
  for (int k = 0; k < 4; ++k) {
    int c = c0 + k, li = r * TS + c;
    if ((m >> c) & 1u) {
      unsigned z = ~m & ((1u << c) - 1u);       // background bits below c
      int start = z ? (32 - __clz((int)z)) : 0; // just after last bg bit
      sl[li] = r * TS + start;                  // run-start label (valid parent <= self)
    } else sl[li] = -1;
  }
  __syncthreads();
  if (r > 0) {
    #pragma unroll
    for (int k = 0; k < 4; ++k) {
      int c = c0 + k, li = r * TS + c;
      if (sl[li] < 0) continue;
      int q = li - TS;
      if (c > 0      && sl[q - 1] >= 0) unite(sl, li, q - 1);
      if (              sl[q]     >= 0) unite(sl, li, q);
      if (c < TS - 1 && sl[q + 1] >= 0) unite(sl, li, q + 1);
    }
  }
  __syncthreads();
  int o[4];
  #pragma unroll
  for (int k = 0; k < 4; ++k) {
    int li = r * TS + c0 + k;
    if (sl[li] < 0) o[k] = BIG_I;
    else {
      int rr = rep(sl, li);
      o[k] = (tileY + (rr >> 5)) * W + tileX + (rr & 31);
    }
  }
  *(int4*)(lab + (tileY + r) * W + tileX + c0) = make_int4(o[0], o[1], o[2], o[3]);
  for (int off = 32; off; off >>= 1) acc += __shfl_down(acc, off, 64);
  if ((t & 63) == 0) red[t >> 6] = acc;
  __syncthreads();
  if (t == 0) atomicAdd(&s->soa, red[0] + red[1] + red[2] + red[3]);
}

// ---- 2: compact border merge (only boundary-crossing edges) ----
// horizontal boundaries: 15 rows (i=32..480), vertical: 15 cols. 15360 threads.
__global__ void k_border(int* __restrict__ lab) {
  int t = blockIdx.x * blockDim.x + threadIdx.x;
  if (t < 7680) {                       // horizontal boundary row
    int b = t >> 9, j = t & 511;
    int i = (b + 1) * TS;
    int p = i * W + j, q = p - W;
    if (lab[p] == BIG_I) return;
    if (j > 0   && lab[q - 1] != BIG_I) unite(lab, p, q - 1);
    if (           lab[q]     != BIG_I) unite(lab, p, q);
    if (j < 511 && lab[q + 1] != BIG_I) unite(lab, p, q + 1);
  } else {                              // vertical boundary col
    int t2 = t - 7680;
    int b = t2 >> 9, i = t2 & 511;
    int j = (b + 1) * TS;
    int p = i * W + j;
    int lp = lab[p], ll = lab[p - 1];
    if (lp != BIG_I && ll != BIG_I) unite(lab, p, p - 1);
    if (i & (TS - 1)) {                 // diagonals not covered by horizontal pass
      if (lp != BIG_I && lab[p - W - 1] != BIG_I) unite(lab, p, p - W - 1);
      if (ll != BIG_I && lab[p - W]     != BIG_I) unite(lab, p - 1, p - W);
    }
  }
}

// ---- 3: row DT (wave-per-row min-plus scan) + fused flatten + scalar init ----
__global__ __launch_bounds__(256) void k_dt_rows(int* __restrict__ lab,
                                                 const float* __restrict__ img,
                                                 const int* __restrict__ pts,
                                                 Scal* __restrict__ s,
                                                 float* __restrict__ dist) {
  int lane = threadIdx.x & 63;
  int row = blockIdx.x * 4 + (threadIdx.x >> 6);
  int el = -1;
  if (lane == 0) {
    int p0 = pts[0] * W + pts[1], p1 = pts[2] * W + pts[3];
    int l0 = lab[p0], l1 = lab[p1];
    int both = (l0 != BIG_I) && (l1 != BIG_I);
    el = both ? root_ro(lab, l1) : -1;
    if (blockIdx.x == 0 && threadIdx.x == 0) {
      s->min_bits = __float_as_uint(BIG_F);
      s->both = both;
      s->r0 = img[p0];
      s->r1 = img[p1];
    }
  }
  el = __shfl(el, 0, 64);
  int4* lp = (int4*)(lab + row * W) + lane * 2;
  int4 a = lp[0], b = lp[1];
  int v[8] = {a.x, a.y, a.z, a.w, b.x, b.y, b.z, b.w};
  #pragma unroll
  for (int k = 0; k < 8; ++k)
    if (v[k] != BIG_I) v[k] = root_ro(lab, v[k]);   // flatten (read-only walk)
  lp[0] = make_int4(v[0], v[1], v[2], v[3]);        // write back final labels
  lp[1] = make_int4(v[4], v[5], v[6], v[7]);
  float d[8];
  #pragma unroll
  for (int k = 0; k < 8; ++k) d[k] = (v[k] == el) ? 0.0f : BIG_F;
  int j0 = lane * 8;
  float pf[8], sb[8];
  float m = INF30;
  #pragma unroll
  for (int k = 0; k < 8; ++k) { m = fminf(m, d[k] - (float)(j0 + k)); pf[k] = m; }
  float tf = m;
  m = INF30;
  #pragma unroll
  for (int k = 7; k >= 0; --k) { m = fminf(m, d[k] + (float)(j0 + k)); sb[k] = m; }
  float tb = m;
  float vv = tf;
  #pragma unroll
  for (int off = 1; off < 64; off <<= 1) {
    float u = __shfl_up(vv, off, 64);
    if (lane >= off) vv = fminf(vv, u);
  }
  float ef = __shfl_up(vv, 1, 64); if (lane == 0) ef = INF30;
  vv = tb;
  #pragma unroll
  for (int off = 1; off < 64; off <<= 1) {
    float u = __shfl_down(vv, off, 64);
    if (lane < 64 - off) vv = fminf(vv, u);
  }
  float eb = __shfl_down(vv, 1, 64); if (lane == 63) eb = INF30;
  float o[8];
  #pragma unroll
  for (int k = 0; k < 8; ++k) {
    float j = (float)(j0 + k);
    o[k] = fminf(j + fminf(ef, pf[k]), -j + fminf(eb, sb[k]));
  }
  float4* dp = (float4*)(dist + row * W) + lane * 2;
  dp[0] = make_float4(o[0], o[1], o[2], o[3]);
  dp[1] = make_float4(o[4], o[5], o[6], o[7]);
}

// ---- 4a: column pass level 1 — per (32-row segment, column) aggregates ----
__global__ void k_dt_colA(const float* __restrict__ dist,
                          float* __restrict__ Af, float* __restrict__ Ab) {
  int t = blockIdx.x * blockDim.x + threadIdx.x;   // 0..8191
  int sg = t >> 9, j = t & 511;
  int i0 = sg * 32;
  float fa = INF30, fb = INF30;
  #pragma unroll 4
  for (int il = 0; il < 32; ++il) {
    float v = dist[(i0 + il) * W + j];
    float fi = (float)(i0 + il);
    fa = fminf(fa, v - fi);
    fb = fminf(fb, v + fi);
  }
  Af[t] = fa;
  Ab[t] = fb;
}

// ---- 4b: column pass level 2 — apply with inline carry scan ----
__global__ __launch_bounds__(256) void k_dt_colB(float* __restrict__ dist,
                                                 const float* __restrict__ Af,
                                                 const float* __restrict__ Ab) {
  int t = blockIdx.x * blockDim.x + threadIdx.x;
  int sg = t >> 9, j = t & 511;
  float cf = INF30, cb = INF30;
  #pragma unroll
  for (int bb = 0; bb < 16; ++bb) {
    if (bb < sg) cf = fminf(cf, Af[bb * W + j]);
    if (bb > sg) cb = fminf(cb, Ab[bb * W + j]);
  }
  int i0 = sg * 32;
  float rr[32], ff[32];
  float m = cf;
  #pragma unroll
  for (int il = 0; il < 32; ++il) {
    rr[il] = dist[(i0 + il) * W + j];
    float fi = (float)(i0 + il);
    m = fminf(m, rr[il] - fi);
    ff[il] = fi + m;
  }
  m = cb;
  #pragma unroll
  for (int il = 31; il >= 0; --il) {
    float fi = (float)(i0 + il);
    m = fminf(m, rr[il] + fi);
    dist[(i0 + il) * W + j] = fminf(ff[il], m - fi);
  }
}

// ---- 5: masked reductions (4 px/thread) + fused finalize ----
__global__ __launch_bounds__(256) void k_reduce(const float* __restrict__ img,
                                                const int* __restrict__ lab,
                                                const float* __restrict__ dist,
                                                const int* __restrict__ pts,
                                                Scal* __restrict__ s,
                                                float* __restrict__ out) {
  __shared__ int ssl;
  __shared__ float smin[4], ssum[4];
  if (threadIdx.x == 0) {
    int p0 = pts[0] * W + pts[1], p1 = pts[2] * W + pts[3];
    int l0 = lab[p0], l1 = lab[p1];
    ssl = (l0 != BIG_I && l1 != BIG_I) ? l0 : -1;  // lab is flattened: l0 is the root
  }
  __syncthreads();
  int slv = ssl;
  int base = (blockIdx.x * 256 + threadIdx.x) * 4;
  int4 lv = *(const int4*)(lab + base);
  float4 dq = *(const float4*)(dist + base);
  float4 iq = *(const float4*)(img + base);
  float dv = BIG_F, cv = 0.0f;
  if (lv.x == slv) { dv = fminf(dv, dq.x); cv += iq.x; }
  if (lv.y == slv) { dv = fminf(dv, dq.y); cv += iq.y; }
  if (lv.z == slv) { dv = fminf(dv, dq.z); cv += iq.z; }
  if (lv.w == slv) { dv = fminf(dv, dq.w); cv += iq.w; }
  for (int o = 32; o; o >>= 1) {
    dv = fminf(dv, __shfl_down(dv, o, 64));
    cv += __shfl_down(cv, o, 64);
  }
  int lane = threadIdx.x & 63, wv = threadIdx.x >> 6;
  if (lane == 0) { smin[wv] = dv; ssum[wv] = cv; }
  __syncthreads();
  if (threadIdx.x == 0) {
    float mm = fminf(fminf(smin[0], smin[1]), fminf(smin[2], smin[3]));
    float su = ssum[0] + ssum[1] + ssum[2] + ssum[3];
    atomicMin(&s->min_bits, __float_as_uint(mm));  // dist >= 0: uint order == float order
    atomicAdd(&s->cluster, su);
    __threadfence();
    unsigned old = atomicAdd(&s->done, 1u);
    if (old == gridDim.x - 1) {
      float fallback = (2.0f - (s->r0 + s->r1)) * 100.0f;
      out[0] = fallback;
      unsigned mb = atomicOr(&s->min_bits, 0u);
      float cl = atomicAdd(&s->cluster, 0.0f);
      int p0 = pts[0] * W + pts[1];
      float min_d = fminf(dist[p0], __uint_as_float(mb));
      float soa = s->soa;
      out[1] = s->both ? (min_d * soa * 10.0f * soa) : fallback;
      out[2] = s->both ? (cl * 90.0f) : fallback;
    }
  }
}

extern "C" void kernel_launch(void* const* d_in, const int* in_sizes, int n_in,
                              void* d_out, int out_size, void* d_ws, size_t ws_size,
                              hipStream_t stream) {
  const float* img = (const float*)d_in[0] + 3 * NPIX;   // result_given[3,0]
  const int* pts = (const int*)d_in[1] + 3 * 4;          // points_given[3]
  float* out = (float*)d_out;

  int* lab = (int*)d_ws;
  float* dist = (float*)d_ws + NPIX;
  char* base = (char*)d_ws + (size_t)2 * NPIX * 4;
  Scal* s = (Scal*)base;
  float* Af = (float*)(base + 64);
  float* Ab = Af + 16 * W;

  hipMemsetAsync(s, 0, 64, stream);   // soa=0, cluster=0, done=0

  k_local<<<256, 256, 0, stream>>>(img, lab, s);
  k_border<<<60, 256, 0, stream>>>(lab);
  k_dt_rows<<<H / 4, 256, 0, stream>>>(lab, img, pts, s, dist);
  k_dt_colA<<<32, 256, 0, stream>>>(dist, Af, Ab);
  k_dt_colB<<<32, 256, 0, stream>>>(dist, Af, Ab);
  k_reduce<<<256, 256, 0, stream>>>(img, lab, dist, pts, s, out);
}